// Round 1
// baseline (764.169 us; speedup 1.0000x reference)
//
#include <hip/hip_runtime.h>
#include <hip/hip_bf16.h>
#include <stdint.h>

// Problem constants (from reference): B=32768, L=1024, S=512, C=16
// Reference simplification: TOPK == NUM_CODES == 16 -> mean_codes is the
// constant mean of all codebook rows -> fold into b1. z/Wp/bp are dead.
//
// out = relu(z2 @ W1[:, :2048].T + b1 + W1[:, 2048:] @ cbmean) @ W2.T + b2

#define DI __device__ __forceinline__

typedef __attribute__((ext_vector_type(8))) short short8;
typedef __attribute__((ext_vector_type(4))) float f32x4;

static DI uint16_t f32_to_bf16(float f) {
    union { float f; uint32_t u; } v; v.f = f;
    uint32_t u = v.u;
    return (uint16_t)((u + 0x7FFFu + ((u >> 16) & 1u)) >> 16);
}

// ---------------------------------------------------------------- convert z2
__global__ void k_convert_z2(const float* __restrict__ z2,
                             uint16_t* __restrict__ dst, int n8) {
    int i = blockIdx.x * blockDim.x + threadIdx.x;
    int stride = gridDim.x * blockDim.x;
    for (; i < n8; i += stride) {
        const float4* p = (const float4*)z2 + (size_t)i * 2;
        float4 a = p[0], b = p[1];
        union { short8 v; uint16_t u[8]; } o;
        o.u[0] = f32_to_bf16(a.x); o.u[1] = f32_to_bf16(a.y);
        o.u[2] = f32_to_bf16(a.z); o.u[3] = f32_to_bf16(a.w);
        o.u[4] = f32_to_bf16(b.x); o.u[5] = f32_to_bf16(b.y);
        o.u[6] = f32_to_bf16(b.z); o.u[7] = f32_to_bf16(b.w);
        *(short8*)(dst + (size_t)i * 8) = o.v;
    }
}

// ------------------------------------------------- prep: weights + fused bias
// grid = 1024 blocks (one per output row n), 256 threads
__global__ void k_prep(const float* __restrict__ codebook,
                       const float* __restrict__ W1,
                       const float* __restrict__ b1,
                       const float* __restrict__ W2,
                       uint16_t* __restrict__ W1z,
                       uint16_t* __restrict__ W2b,
                       float* __restrict__ b1p) {
    int n = blockIdx.x;
    int t = threadIdx.x;
    // convert W1[:, :2048] row n  (256 threads x 8 elems)
    {
        const float* src = W1 + (size_t)n * 2560 + t * 8;
        float4 a = *(const float4*)src;
        float4 b = *(const float4*)(src + 4);
        union { short8 v; uint16_t u[8]; } o;
        o.u[0] = f32_to_bf16(a.x); o.u[1] = f32_to_bf16(a.y);
        o.u[2] = f32_to_bf16(a.z); o.u[3] = f32_to_bf16(a.w);
        o.u[4] = f32_to_bf16(b.x); o.u[5] = f32_to_bf16(b.y);
        o.u[6] = f32_to_bf16(b.z); o.u[7] = f32_to_bf16(b.w);
        *(short8*)(W1z + (size_t)n * 2048 + t * 8) = o.v;
    }
    // convert W2 row n (first 128 threads x 8 elems)
    if (t < 128) {
        const float* src = W2 + (size_t)n * 1024 + t * 8;
        float4 a = *(const float4*)src;
        float4 b = *(const float4*)(src + 4);
        union { short8 v; uint16_t u[8]; } o;
        o.u[0] = f32_to_bf16(a.x); o.u[1] = f32_to_bf16(a.y);
        o.u[2] = f32_to_bf16(a.z); o.u[3] = f32_to_bf16(a.w);
        o.u[4] = f32_to_bf16(b.x); o.u[5] = f32_to_bf16(b.y);
        o.u[6] = f32_to_bf16(b.z); o.u[7] = f32_to_bf16(b.w);
        *(short8*)(W2b + (size_t)n * 1024 + t * 8) = o.v;
    }
    // b1p[n] = b1[n] + sum_s W1[n, 2048+s] * mean_c codebook[c, s]   (fp32)
    float part = 0.f;
    for (int s = t; s < 512; s += 256) {
        float cm = 0.f;
        #pragma unroll
        for (int c = 0; c < 16; ++c) cm += codebook[c * 512 + s];
        part += W1[(size_t)n * 2560 + 2048 + s] * (cm * (1.f / 16.f));
    }
    #pragma unroll
    for (int off = 32; off; off >>= 1) part += __shfl_down(part, off);
    __shared__ float red[4];
    if ((t & 63) == 0) red[t >> 6] = part;
    __syncthreads();
    if (t == 0) b1p[n] = b1[n] + red[0] + red[1] + red[2] + red[3];
}

// -------------------------------------------------------------- bf16 GEMM-BT
// C[M,N] = epi(A[M,K] @ Bm[N,K].T + bias[N]); A,Bm bf16 row-major (K contig)
// m97 structure: 128x128 tile, BK=32, 4 waves each owning a 64x64 subtile of
// 4x4 16x16x32 MFMA fragments; global_load_lds width 16; 2 barriers/K-step.
DI void gl_lds16(const uint16_t* g, uint16_t* l) {
    __builtin_amdgcn_global_load_lds(
        (const __attribute__((address_space(1))) unsigned int*)g,
        (__attribute__((address_space(3))) unsigned int*)l, 16, 0, 0);
}

template <int EPI>  // 0: relu+bias -> bf16 ; 1: bias -> fp32
__global__ __launch_bounds__(256) void k_gemm_bt(
    const uint16_t* __restrict__ A, const uint16_t* __restrict__ Bm,
    const float* __restrict__ bias, void* __restrict__ Cout,
    int M, int N, int K) {
    __shared__ uint16_t As[128 * 32];
    __shared__ uint16_t Bs[128 * 32];

    const int ntiles = N >> 7;
    const int mt = blockIdx.x / ntiles;
    const int nt = blockIdx.x % ntiles;
    const int t = threadIdx.x, lane = t & 63, wid = t >> 6;
    const int wr = wid >> 1, wc = wid & 1;
    const int brow = mt << 7, bcol = nt << 7;

    f32x4 acc[4][4] = {};

    // staging: thread t, issue i in {0,1} per tile:
    //   flat elem e = (i*256+t)*8 -> row = 64*i + t/4, col = (t%4)*8
    const int srow = t >> 2;
    const int scol = (t & 3) * 8;
    const uint16_t* gA0 = A + (size_t)(brow + srow) * K + scol;
    const uint16_t* gA1 = A + (size_t)(brow + 64 + srow) * K + scol;
    const uint16_t* gB0 = Bm + (size_t)(bcol + srow) * K + scol;
    const uint16_t* gB1 = Bm + (size_t)(bcol + 64 + srow) * K + scol;
    uint16_t* lA0 = As + wid * 512;         // wave-uniform LDS bases
    uint16_t* lA1 = As + 2048 + wid * 512;
    uint16_t* lB0 = Bs + wid * 512;
    uint16_t* lB1 = Bs + 2048 + wid * 512;

    const int ar = lane & 15;
    const int ko = (lane >> 4) * 8;
    const int nk = K >> 5;

    for (int kt = 0; kt < nk; ++kt) {
        if (kt) __syncthreads();
        gl_lds16(gA0, lA0);
        gl_lds16(gA1, lA1);
        gl_lds16(gB0, lB0);
        gl_lds16(gB1, lB1);
        gA0 += 32; gA1 += 32; gB0 += 32; gB1 += 32;
        __syncthreads();  // implies s_waitcnt vmcnt(0) lgkmcnt(0)

        short8 af[4], bfr[4];
        #pragma unroll
        for (int i = 0; i < 4; ++i)
            af[i] = *(const short8*)(As + (wr * 64 + i * 16 + ar) * 32 + ko);
        #pragma unroll
        for (int j = 0; j < 4; ++j)
            bfr[j] = *(const short8*)(Bs + (wc * 64 + j * 16 + ar) * 32 + ko);
        #pragma unroll
        for (int i = 0; i < 4; ++i)
            #pragma unroll
            for (int j = 0; j < 4; ++j)
                acc[i][j] = __builtin_amdgcn_mfma_f32_16x16x32_bf16(
                    af[i], bfr[j], acc[i][j], 0, 0, 0);
    }

    // epilogue: D elem (row=(lane>>4)*4+r, col=lane&15) per fragment (m89)
    const int orow0 = brow + wr * 64 + (lane >> 4) * 4;
    const int ocol0 = bcol + wc * 64 + (lane & 15);
    uint16_t* Cb = (uint16_t*)Cout;
    float* Cf = (float*)Cout;
    #pragma unroll
    for (int j = 0; j < 4; ++j) {
        const int n = ocol0 + j * 16;
        const float bj = bias[n];
        #pragma unroll
        for (int i = 0; i < 4; ++i) {
            const int m0 = orow0 + i * 16;
            #pragma unroll
            for (int r = 0; r < 4; ++r) {
                float v = acc[i][j][r] + bj;
                if (EPI == 0) {
                    v = fmaxf(v, 0.f);
                    Cb[(size_t)(m0 + r) * N + n] = f32_to_bf16(v);
                } else {
                    Cf[(size_t)(m0 + r) * N + n] = v;
                }
            }
        }
    }
}

// ------------------------------------------------------------------ launcher
extern "C" void kernel_launch(void* const* d_in, const int* in_sizes, int n_in,
                              void* d_out, int out_size, void* d_ws, size_t ws_size,
                              hipStream_t stream) {
    (void)in_sizes; (void)n_in; (void)out_size; (void)ws_size;
    // inputs: z, z2, codebook, Wp, bp, W1, b1, W2, b2  (z/Wp/bp dead)
    const float* z2 = (const float*)d_in[1];
    const float* cb = (const float*)d_in[2];
    const float* W1 = (const float*)d_in[5];
    const float* b1 = (const float*)d_in[6];
    const float* W2 = (const float*)d_in[7];
    const float* b2 = (const float*)d_in[8];
    float* out = (float*)d_out;

    char* ws = (char*)d_ws;
    uint16_t* h   = (uint16_t*)ws;                                  // 64 MiB
    uint16_t* W1z = (uint16_t*)(ws + (size_t)67108864);             // 4 MiB
    uint16_t* W2b = (uint16_t*)(ws + (size_t)67108864 + 4194304);   // 2 MiB
    float*    b1p = (float*)(ws + (size_t)67108864 + 4194304 + 2097152);
    // z2 bf16 aliased into d_out (exactly 128 MiB); fully overwritten by GEMM2
    uint16_t* z2b = (uint16_t*)d_out;

    k_convert_z2<<<2048, 256, 0, stream>>>(z2, z2b, 67108864 / 8);
    k_prep<<<1024, 256, 0, stream>>>(cb, W1, b1, W2, W1z, W2b, b1p);
    // GEMM1: h = relu(z2 @ W1z.T + b1p)   M=32768 N=1024 K=2048
    k_gemm_bt<0><<<dim3(256 * 8), 256, 0, stream>>>(z2b, W1z, b1p, h,
                                                    32768, 1024, 2048);
    // GEMM2: out = h @ W2.T + b2          M=32768 N=1024 K=1024
    k_gemm_bt<1><<<dim3(256 * 8), 256, 0, stream>>>(h, W2b, b2, out,
                                                    32768, 1024, 1024);
}